// Round 4
// baseline (273.512 us; speedup 1.0000x reference)
//
#include <hip/hip_runtime.h>

// GAT attention scores, R12: split the stuck range_sum into escore/accum.
//
// Evidence: range_sum is pinned at 90-99us across THREE memory structures
// (R8: 2 random TA gathers; R9: 1; R11: 0 - all reads from LDS tiles),
// with VALUBusy<=8%, HBM<=2%, conflicts ~0. The wall is not the gathers;
// it is the per-edge accumulation machinery (8x cvt/add/leaky/exp/LDS-
// atomic in a thread-serial loop) -- or the tile phase machinery. No
// counter distinguishes them, so R12 splits the kernel so the per-
// dispatch timer ablates it:
//   escore: tiles -> per-edge fp16x8 post-leaky scores, coalesced stores
//           (no atomics, no exp)  => dur = tile+score cost T
//   accum : coalesced binned+sc16 streams -> exp + LDS atomic + partial
//           (no tiles, 8KB LDS -> high occupancy) => dur = accum cost A
// sc16 lives in the out-region scratch (26MB; out fully rewritten by
// edge_out afterwards). t stored post-leaky in fp16 (range-safe; exp(t)
// in fp16 would overflow). edge_out unchanged (recomputes t exactly as
// R11, so output-path numerics identical; only ln-sum sees t16 rounding).
//
// ws (~9.0MB): s2h .8M | combh 1.6M | binned 6.48M | tstart/tend/gtot 59K
// out-region scratch (consumed before edge_out rewrites all of out):
//   sc16 25.95M | partial 6.4M | counts 2.5M | bbase 2.5M  (37.4 < 51.2)

constexpr int NN = 50000;
constexpr int NE = 1600000;
constexpr int F  = 32;
constexpr int H  = 8;
constexpr float ALPHA = 0.2f;
constexpr float EPS   = 1e-12f;

constexpr int RSH     = 8;
constexpr int RNODES  = 1 << RSH;                   // 256 nodes/row-range
constexpr int NR      = (NN + RNODES - 1) / RNODES; // 196
constexpr int CSH     = 11;
constexpr int CNODES  = 1 << CSH;                   // 2048 nodes/col-tile (32KB fp16)
constexpr int NCX     = (NN + CNODES - 1) / CNODES; // 25
constexpr int NBIN    = NR * NCX;                   // 4900
constexpr int NB2     = 128;                        // blocks in bin passes
constexpr int CHUNK2  = NE / NB2;                   // 12500
constexpr int SC      = 4;                          // stripes
constexpr int ESZ     = NE + 4 * NBIN + 64;         // binned/sc16 entry count

typedef _Float16 v8h __attribute__((ext_vector_type(8)));

__global__ __launch_bounds__(256) void node_proj_kernel(
    const float* __restrict__ x, const float* __restrict__ aa,
    float* __restrict__ combh, float* __restrict__ s2h)
{
    __shared__ float aal[H * 2 * F];
    for (int i = threadIdx.x; i < H * 2 * F; i += 256) aal[i] = aa[i];
    __syncthreads();

    int n = blockIdx.x * 256 + threadIdx.x;
    if (n >= NN) return;

    const float4* xp = reinterpret_cast<const float4*>(x + (size_t)n * F);
    float4 xv[F / 4];
#pragma unroll
    for (int i = 0; i < F / 4; ++i) xv[i] = xp[i];

    float o1[H], o2[H];
#pragma unroll
    for (int h = 0; h < H; ++h) {
        const float* a1 = &aal[h * 2 * F];
        const float* a2 = a1 + F;
        float acc1 = 0.f, acc2 = 0.f;
#pragma unroll
        for (int i = 0; i < F / 4; ++i) {
            acc1 = fmaf(a1[4*i+0], xv[i].x, acc1);
            acc1 = fmaf(a1[4*i+1], xv[i].y, acc1);
            acc1 = fmaf(a1[4*i+2], xv[i].z, acc1);
            acc1 = fmaf(a1[4*i+3], xv[i].w, acc1);
            acc2 = fmaf(a2[4*i+0], xv[i].x, acc2);
            acc2 = fmaf(a2[4*i+1], xv[i].y, acc2);
            acc2 = fmaf(a2[4*i+2], xv[i].z, acc2);
            acc2 = fmaf(a2[4*i+3], xv[i].w, acc2);
        }
        o1[h] = acc1; o2[h] = acc2;
    }

    v8h s1v, s2v;
#pragma unroll
    for (int h = 0; h < H; ++h) { s1v[h] = (_Float16)o1[h]; s2v[h] = (_Float16)o2[h]; }
    reinterpret_cast<v8h*>(combh)[(size_t)n * 2] = s1v;   // lnrech slot filled later
    reinterpret_cast<v8h*>(s2h)[n] = s2v;
}

// counts layout: counts[blk * NBIN + bin]
__global__ __launch_bounds__(256) void bin_count_kernel(
    const int* __restrict__ row, const int* __restrict__ col,
    int* __restrict__ counts)
{
    __shared__ int cnt[NBIN];
    for (int i = threadIdx.x; i < NBIN; i += 256) cnt[i] = 0;
    __syncthreads();
    const int base = blockIdx.x * CHUNK2;
    const int4* r4 = reinterpret_cast<const int4*>(row + base);
    const int4* c4 = reinterpret_cast<const int4*>(col + base);
    for (int i = threadIdx.x; i < CHUNK2 / 4; i += 256) {
        int4 r = r4[i], c = c4[i];
        atomicAdd(&cnt[(r.x >> RSH) * NCX + (c.x >> CSH)], 1);
        atomicAdd(&cnt[(r.y >> RSH) * NCX + (c.y >> CSH)], 1);
        atomicAdd(&cnt[(r.z >> RSH) * NCX + (c.z >> CSH)], 1);
        atomicAdd(&cnt[(r.w >> RSH) * NCX + (c.w >> CSH)], 1);
    }
    __syncthreads();
    int* myrow = counts + (size_t)blockIdx.x * NBIN;
    for (int i = threadIdx.x; i < NBIN; i += 256) myrow[i] = cnt[i];
}

// per-bin totals
__global__ __launch_bounds__(256) void scan_a_kernel(
    const int* __restrict__ counts, int* __restrict__ gtot)
{
    int b = blockIdx.x * 256 + threadIdx.x;
    if (b >= NBIN) return;
    int s = 0;
    for (int k = 0; k < NB2; ++k) s += counts[(size_t)k * NBIN + b];
    gtot[b] = s;
}

// single block: exclusive scan of 4-aligned bin sizes -> tstart/tend
__global__ __launch_bounds__(1024) void scan_b_kernel(
    const int* __restrict__ gtot, int* __restrict__ tstart, int* __restrict__ tend)
{
    __shared__ int tot[NBIN];
    __shared__ int tp[1024];
    const int t = threadIdx.x;
    for (int b = t; b < NBIN; b += 1024) tot[b] = gtot[b];
    __syncthreads();
    constexpr int PB = (NBIN + 1023) / 1024;   // 5
    int s = 0;
#pragma unroll
    for (int j = 0; j < PB; ++j) {
        int b = t * PB + j;
        if (b < NBIN) s += (tot[b] + 3) & ~3;  // pad each bin to 4 entries (16B)
    }
    tp[t] = s;
    __syncthreads();
    for (int off = 1; off < 1024; off <<= 1) {
        int v = (t >= off) ? tp[t - off] : 0;
        __syncthreads();
        tp[t] += v;
        __syncthreads();
    }
    int run = tp[t] - s;                       // exclusive prefix
#pragma unroll
    for (int j = 0; j < PB; ++j) {
        int b = t * PB + j;
        if (b < NBIN) {
            tstart[b] = run;
            tend[b] = run + tot[b];
            run += (tot[b] + 3) & ~3;
        }
    }
    if (t == 1023) tstart[NBIN] = tp[1023];
}

// per-(block,bin) bases
__global__ __launch_bounds__(256) void scan_c_kernel(
    const int* __restrict__ counts, const int* __restrict__ tstart,
    int* __restrict__ bbase)
{
    int b = blockIdx.x * 256 + threadIdx.x;
    if (b >= NBIN) return;
    int run = tstart[b];
    for (int k = 0; k < NB2; ++k) {
        bbase[(size_t)k * NBIN + b] = run;
        run += counts[(size_t)k * NBIN + b];
    }
}

__global__ __launch_bounds__(256) void bin_scatter_kernel(
    const int* __restrict__ row, const int* __restrict__ col,
    const int* __restrict__ bbase, const int* __restrict__ tstart,
    const int* __restrict__ tend, unsigned* __restrict__ binned)
{
    // block 0 fills alignment pads with sentinels (ws is 0xAA-poisoned!)
    if (blockIdx.x == 0) {
        for (int b = threadIdx.x; b < NBIN; b += 256) {
            for (int p = tend[b]; p < tstart[b + 1]; ++p)
                binned[p] = 0xFFFFFFFFu;
        }
    }
    __shared__ int cur[NBIN];
    const int* myb = bbase + (size_t)blockIdx.x * NBIN;
    for (int i = threadIdx.x; i < NBIN; i += 256) cur[i] = myb[i];
    __syncthreads();
    const int base = blockIdx.x * CHUNK2;
    const int4* r4 = reinterpret_cast<const int4*>(row + base);
    const int4* c4 = reinterpret_cast<const int4*>(col + base);
    for (int i = threadIdx.x; i < CHUNK2 / 4; i += 256) {
        int4 r = r4[i], c = c4[i];
        int rr[4] = {r.x, r.y, r.z, r.w};
        int cc[4] = {c.x, c.y, c.z, c.w};
#pragma unroll
        for (int k = 0; k < 4; ++k) {
            int bin = (rr[k] >> RSH) * NCX + (cc[k] >> CSH);
            int pos = atomicAdd(&cur[bin], 1);
            binned[pos] = ((unsigned)rr[k] << 16) | (unsigned)cc[k];
        }
    }
}

// grid (NR, SC), 512 thr: LDS tiles -> per-edge post-leaky scores t (fp16x8),
// stored coalesced at the edge's binned position. NO atomics, NO exp.
__global__ __launch_bounds__(512) void escore_kernel(
    const unsigned* __restrict__ binned, const int* __restrict__ tstart,
    const float* __restrict__ combh, const float* __restrict__ s2h,
    float* __restrict__ sc16)
{
    __shared__ v8h s1t[RNODES];        // 4 KB
    __shared__ v8h s2t[CNODES];        // 32 KB
    const int rx = blockIdx.x;
    const int rbase = rx << RSH;
    const v8h* combv = reinterpret_cast<const v8h*>(combh);
    const v8h* s2v   = reinterpret_cast<const v8h*>(s2h);
    v8h* scv = reinterpret_cast<v8h*>(sc16);

    for (int d = threadIdx.x; d < RNODES; d += 512) {
        int n = rbase + d;
        if (n >= NN) n = NN - 1;
        s1t[d] = combv[(size_t)n * 2];
    }

    const uint4* b4 = reinterpret_cast<const uint4*>(binned);
    for (int cx = blockIdx.y; cx < NCX; cx += SC) {
        __syncthreads();                       // protect s2t from prev readers
        const int cb = cx << CSH;
        for (int j = threadIdx.x; j < CNODES; j += 512) {
            int n = cb + j;
            if (n >= NN) n = NN - 1;
            s2t[j] = s2v[n];
        }
        __syncthreads();
        const int bin = rx * NCX + cx;
        const int p0 = tstart[bin] >> 2, p1 = tstart[bin + 1] >> 2;
        for (int i = p0 + threadIdx.x; i < p1; i += 512) {
            uint4 q = b4[i];
            unsigned pk[4] = {q.x, q.y, q.z, q.w};
            v8h tv[4]; bool ok[4];
#pragma unroll
            for (int k = 0; k < 4; ++k) {
                unsigned d = (pk[k] >> 16) - (unsigned)rbase;
                ok[k] = d < (unsigned)RNODES;            // sentinel pad
                unsigned dcl = ok[k] ? d : 0u;
                unsigned cl  = ok[k] ? ((pk[k] & 0xFFFFu) - (unsigned)cb) : 0u;
                v8h a = s1t[dcl];
                v8h b = s2t[cl];
#pragma unroll
                for (int h = 0; h < H; ++h) {
                    float t = (float)a[h] + (float)b[h];
                    t = fmaxf(t, ALPHA * t);             // leaky here, once
                    tv[k][h] = (_Float16)t;
                }
            }
#pragma unroll
            for (int k = 0; k < 4; ++k)
                if (ok[k]) scv[(size_t)i * 4 + k] = tv[k];  // coalesced 64B/thread
        }
    }
}

// grid (NR, SC), 512 thr: coalesced binned+sc16 streams; exp + LDS atomic
// + partial writeout ONLY. 8 KB LDS -> high occupancy.
__global__ __launch_bounds__(512) void accum_kernel(
    const unsigned* __restrict__ binned, const int* __restrict__ tstart,
    const float* __restrict__ sc16, float* __restrict__ partial)
{
    __shared__ float acc[RNODES * H];   // 8 KB (swizzled)
    for (int i = threadIdx.x; i < RNODES * H; i += 512) acc[i] = 0.f;
    __syncthreads();

    const int rx = blockIdx.x;
    const int rbase = rx << RSH;
    const uint4* b4 = reinterpret_cast<const uint4*>(binned);
    const v8h* scv = reinterpret_cast<const v8h*>(sc16);

    const int s0 = tstart[rx * NCX] >> 2;
    const int s1 = tstart[(rx + 1) * NCX] >> 2;        // whole range span
    for (int i = s0 + blockIdx.y * 512 + threadIdx.x; i < s1; i += SC * 512) {
        uint4 q = b4[i];
        unsigned pk[4] = {q.x, q.y, q.z, q.w};
#pragma unroll
        for (int k = 0; k < 4; ++k) {
            unsigned d = (pk[k] >> 16) - (unsigned)rbase;
            if (d >= (unsigned)RNODES) continue;         // sentinel pad
            v8h t8 = scv[(size_t)i * 4 + k];
            float* ap = &acc[d << 3];
#pragma unroll
            for (int h = 0; h < H; ++h)
                atomicAdd(ap + ((h + d) & 7), __expf((float)t8[h]));  // swizzled
        }
    }
    __syncthreads();

    const int cnt = min(RNODES, NN - rbase);
    float* outp = partial + ((size_t)blockIdx.y * NN + rbase) * H;
    for (int j = threadIdx.x; j < cnt * H; j += 512) {
        int d = j >> 3, h = j & 7;
        outp[j] = acc[(d << 3) + ((h + d) & 7)];       // unswizzle
    }
}

// per-node: fold stripe partials, store lnrec = -log(sum+eps) as fp16
__global__ __launch_bounds__(256) void node_final_kernel(
    const float* __restrict__ partial, float* __restrict__ combh)
{
    int n = blockIdx.x * 256 + threadIdx.x;
    if (n >= NN) return;
    const float4* p4 = reinterpret_cast<const float4*>(partial);
    float4 lo = p4[(size_t)n * 2], hi = p4[(size_t)n * 2 + 1];
#pragma unroll
    for (int s = 1; s < SC; ++s) {
        float4 a = p4[(size_t)s * (NN * 2) + n * 2];
        float4 b = p4[(size_t)s * (NN * 2) + n * 2 + 1];
        lo.x += a.x; lo.y += a.y; lo.z += a.z; lo.w += a.w;
        hi.x += b.x; hi.y += b.y; hi.z += b.z; hi.w += b.w;
    }
    float s8[8] = {lo.x, lo.y, lo.z, lo.w, hi.x, hi.y, hi.z, hi.w};
    v8h lnh;
#pragma unroll
    for (int h = 0; h < H; ++h) lnh[h] = (_Float16)(-__logf(s8[h] + EPS));
    reinterpret_cast<v8h*>(combh)[(size_t)n * 2 + 1] = lnh;
}

// eid-order: 4 edges/thread; 2 miss streams (comb line + s2 line);
// coalesced float4 stores per h-plane.
__global__ __launch_bounds__(256) void edge_out_kernel(
    const int* __restrict__ row, const int* __restrict__ col,
    const float* __restrict__ combh, const float* __restrict__ s2h,
    float* __restrict__ out)
{
    int e0 = (blockIdx.x * 256 + threadIdx.x) * 4;
    if (e0 >= NE) return;
    int4 r4 = *reinterpret_cast<const int4*>(row + e0);
    int4 c4 = *reinterpret_cast<const int4*>(col + e0);
    int rr[4] = {r4.x, r4.y, r4.z, r4.w};
    int cc[4] = {c4.x, c4.y, c4.z, c4.w};
    const v8h* combv = reinterpret_cast<const v8h*>(combh);
    const v8h* s2v   = reinterpret_cast<const v8h*>(s2h);

    float res[4][H];
#pragma unroll
    for (int k = 0; k < 4; ++k) {
        v8h a  = combv[(size_t)rr[k] * 2];
        v8h ln = combv[(size_t)rr[k] * 2 + 1];
        v8h b  = s2v[cc[k]];
#pragma unroll
        for (int h = 0; h < H; ++h) {
            float t = (float)a[h] + (float)b[h];
            t = fmaxf(t, ALPHA * t);
            res[k][h] = __expf(t + (float)ln[h]);   // == exp(leaky(t)) / (sum+eps)
        }
    }
#pragma unroll
    for (int h = 0; h < H; ++h) {
        *reinterpret_cast<float4*>(out + (size_t)h * NE + e0) =
            make_float4(res[0][h], res[1][h], res[2][h], res[3][h]);
    }
}

extern "C" void kernel_launch(void* const* d_in, const int* in_sizes, int n_in,
                              void* d_out, int out_size, void* d_ws, size_t ws_size,
                              hipStream_t stream) {
    const float* x   = (const float*)d_in[0];
    const float* aa  = (const float*)d_in[1];
    const int*   row = (const int*)d_in[2];
    const int*   col = (const int*)d_in[3];
    float* out = (float*)d_out;

    // ws (~9.0 MB)
    float* s2h   = (float*)d_ws;                          // NN*4 floats
    float* combh = s2h + (size_t)NN * 4;                  // NN*8 floats
    unsigned* binned = (unsigned*)(combh + (size_t)NN * 8); // ESZ uints
    int* tstart  = (int*)(binned + ESZ);                  // NBIN+1
    int* tend    = tstart + NBIN + 1;                     // NBIN
    int* gtot    = tend + NBIN;                           // NBIN

    // out-region scratch (fully consumed before edge_out rewrites out)
    float* sc16    = out;                                 // ESZ*4 floats (25.95M)
    float* partial = sc16 + (size_t)ESZ * 4;              // SC*NN*H floats (6.4M)
    int* counts = (int*)(partial + (size_t)SC * NN * H);  // NB2*NBIN (2.5M)
    int* bbase  = counts + (size_t)NB2 * NBIN;            // NB2*NBIN (2.5M)

    node_proj_kernel<<<(NN + 255) / 256, 256, 0, stream>>>(x, aa, combh, s2h);
    bin_count_kernel<<<NB2, 256, 0, stream>>>(row, col, counts);
    scan_a_kernel<<<(NBIN + 255) / 256, 256, 0, stream>>>(counts, gtot);
    scan_b_kernel<<<1, 1024, 0, stream>>>(gtot, tstart, tend);
    scan_c_kernel<<<(NBIN + 255) / 256, 256, 0, stream>>>(counts, tstart, bbase);
    bin_scatter_kernel<<<NB2, 256, 0, stream>>>(row, col, bbase, tstart, tend, binned);
    escore_kernel<<<dim3(NR, SC), 512, 0, stream>>>(binned, tstart, combh, s2h, sc16);
    accum_kernel<<<dim3(NR, SC), 512, 0, stream>>>(binned, tstart, sc16, partial);
    node_final_kernel<<<(NN + 255) / 256, 256, 0, stream>>>(partial, combh);
    edge_out_kernel<<<(NE / 4 + 255) / 256, 256, 0, stream>>>(row, col, combh, s2h, out);
}

// Round 5
// 229.547 us; speedup vs baseline: 1.1915x; 1.1915x over previous
//
#include <hip/hip_runtime.h>

// GAT attention scores, R13: kill the per-edge LDS fp atomics.
//
// R12 ablation: escore (tiles+scores, coalesced) = 23us; accum (exp +
// 8 fp32 LDS atomicAdd per edge, everything else coalesced) = 88.7us
// with ALL counters idle (VALU 3%, HBM 4%, conflicts 0). The wall is
// the fp32 LDS atomic machinery itself (slow DS RMW or CAS loop under
// ~8-way same-address contention) - invariant 88-99us across R8-R12.
//
// R13: node_sort (1 block/range) histograms the range's 256 nodes (1 int
// atomic/edge), scans, and emits a node-sorted index list sc2idx (+1 rtn
// int atomic/edge). accum2 then does ATOMIC-FREE per-node segment sums:
// thread n sums exp(sc16[sc2idx[j]]) over its ~32 edges (range-local L2
// gathers - the access class R9 proved free) and writes lnrec directly.
// accum + node_final + partial are deleted.
//
// ws (15.82MB <= 16.0 proven R8): s2h .8M | combh 1.6M | binned 6.48M |
//   sc2idx 6.48M | nstart .2M | ncnt .2M | tstart/tend/gtot 59K
// out-region scratch (consumed before edge_out rewrites all of out):
//   sc16 25.9M | counts 2.5M | bbase 2.5M  (30.9 < 51.2)

constexpr int NN = 50000;
constexpr int NE = 1600000;
constexpr int F  = 32;
constexpr int H  = 8;
constexpr float ALPHA = 0.2f;
constexpr float EPS   = 1e-12f;

constexpr int RSH     = 8;
constexpr int RNODES  = 1 << RSH;                   // 256 nodes/row-range
constexpr int NR      = (NN + RNODES - 1) / RNODES; // 196
constexpr int CSH     = 11;
constexpr int CNODES  = 1 << CSH;                   // 2048 nodes/col-tile (32KB fp16)
constexpr int NCX     = (NN + CNODES - 1) / CNODES; // 25
constexpr int NBIN    = NR * NCX;                   // 4900
constexpr int NB2     = 128;                        // blocks in bin passes
constexpr int CHUNK2  = NE / NB2;                   // 12500
constexpr int SC      = 4;                          // escore col-tile stripes
constexpr int ESZ     = NE + 4 * NBIN + 64;         // binned/sc16 entry count

typedef _Float16 v8h __attribute__((ext_vector_type(8)));

__global__ __launch_bounds__(256) void node_proj_kernel(
    const float* __restrict__ x, const float* __restrict__ aa,
    float* __restrict__ combh, float* __restrict__ s2h)
{
    __shared__ float aal[H * 2 * F];
    for (int i = threadIdx.x; i < H * 2 * F; i += 256) aal[i] = aa[i];
    __syncthreads();

    int n = blockIdx.x * 256 + threadIdx.x;
    if (n >= NN) return;

    const float4* xp = reinterpret_cast<const float4*>(x + (size_t)n * F);
    float4 xv[F / 4];
#pragma unroll
    for (int i = 0; i < F / 4; ++i) xv[i] = xp[i];

    float o1[H], o2[H];
#pragma unroll
    for (int h = 0; h < H; ++h) {
        const float* a1 = &aal[h * 2 * F];
        const float* a2 = a1 + F;
        float acc1 = 0.f, acc2 = 0.f;
#pragma unroll
        for (int i = 0; i < F / 4; ++i) {
            acc1 = fmaf(a1[4*i+0], xv[i].x, acc1);
            acc1 = fmaf(a1[4*i+1], xv[i].y, acc1);
            acc1 = fmaf(a1[4*i+2], xv[i].z, acc1);
            acc1 = fmaf(a1[4*i+3], xv[i].w, acc1);
            acc2 = fmaf(a2[4*i+0], xv[i].x, acc2);
            acc2 = fmaf(a2[4*i+1], xv[i].y, acc2);
            acc2 = fmaf(a2[4*i+2], xv[i].z, acc2);
            acc2 = fmaf(a2[4*i+3], xv[i].w, acc2);
        }
        o1[h] = acc1; o2[h] = acc2;
    }

    v8h s1v, s2v;
#pragma unroll
    for (int h = 0; h < H; ++h) { s1v[h] = (_Float16)o1[h]; s2v[h] = (_Float16)o2[h]; }
    reinterpret_cast<v8h*>(combh)[(size_t)n * 2] = s1v;   // lnrech slot filled later
    reinterpret_cast<v8h*>(s2h)[n] = s2v;
}

// counts layout: counts[blk * NBIN + bin]
__global__ __launch_bounds__(256) void bin_count_kernel(
    const int* __restrict__ row, const int* __restrict__ col,
    int* __restrict__ counts)
{
    __shared__ int cnt[NBIN];
    for (int i = threadIdx.x; i < NBIN; i += 256) cnt[i] = 0;
    __syncthreads();
    const int base = blockIdx.x * CHUNK2;
    const int4* r4 = reinterpret_cast<const int4*>(row + base);
    const int4* c4 = reinterpret_cast<const int4*>(col + base);
    for (int i = threadIdx.x; i < CHUNK2 / 4; i += 256) {
        int4 r = r4[i], c = c4[i];
        atomicAdd(&cnt[(r.x >> RSH) * NCX + (c.x >> CSH)], 1);
        atomicAdd(&cnt[(r.y >> RSH) * NCX + (c.y >> CSH)], 1);
        atomicAdd(&cnt[(r.z >> RSH) * NCX + (c.z >> CSH)], 1);
        atomicAdd(&cnt[(r.w >> RSH) * NCX + (c.w >> CSH)], 1);
    }
    __syncthreads();
    int* myrow = counts + (size_t)blockIdx.x * NBIN;
    for (int i = threadIdx.x; i < NBIN; i += 256) myrow[i] = cnt[i];
}

// per-bin totals
__global__ __launch_bounds__(256) void scan_a_kernel(
    const int* __restrict__ counts, int* __restrict__ gtot)
{
    int b = blockIdx.x * 256 + threadIdx.x;
    if (b >= NBIN) return;
    int s = 0;
    for (int k = 0; k < NB2; ++k) s += counts[(size_t)k * NBIN + b];
    gtot[b] = s;
}

// single block: exclusive scan of 4-aligned bin sizes -> tstart/tend
__global__ __launch_bounds__(1024) void scan_b_kernel(
    const int* __restrict__ gtot, int* __restrict__ tstart, int* __restrict__ tend)
{
    __shared__ int tot[NBIN];
    __shared__ int tp[1024];
    const int t = threadIdx.x;
    for (int b = t; b < NBIN; b += 1024) tot[b] = gtot[b];
    __syncthreads();
    constexpr int PB = (NBIN + 1023) / 1024;   // 5
    int s = 0;
#pragma unroll
    for (int j = 0; j < PB; ++j) {
        int b = t * PB + j;
        if (b < NBIN) s += (tot[b] + 3) & ~3;  // pad each bin to 4 entries (16B)
    }
    tp[t] = s;
    __syncthreads();
    for (int off = 1; off < 1024; off <<= 1) {
        int v = (t >= off) ? tp[t - off] : 0;
        __syncthreads();
        tp[t] += v;
        __syncthreads();
    }
    int run = tp[t] - s;                       // exclusive prefix
#pragma unroll
    for (int j = 0; j < PB; ++j) {
        int b = t * PB + j;
        if (b < NBIN) {
            tstart[b] = run;
            tend[b] = run + tot[b];
            run += (tot[b] + 3) & ~3;
        }
    }
    if (t == 1023) tstart[NBIN] = tp[1023];
}

// per-(block,bin) bases
__global__ __launch_bounds__(256) void scan_c_kernel(
    const int* __restrict__ counts, const int* __restrict__ tstart,
    int* __restrict__ bbase)
{
    int b = blockIdx.x * 256 + threadIdx.x;
    if (b >= NBIN) return;
    int run = tstart[b];
    for (int k = 0; k < NB2; ++k) {
        bbase[(size_t)k * NBIN + b] = run;
        run += counts[(size_t)k * NBIN + b];
    }
}

__global__ __launch_bounds__(256) void bin_scatter_kernel(
    const int* __restrict__ row, const int* __restrict__ col,
    const int* __restrict__ bbase, const int* __restrict__ tstart,
    const int* __restrict__ tend, unsigned* __restrict__ binned)
{
    // block 0 fills alignment pads with sentinels (ws is 0xAA-poisoned!)
    if (blockIdx.x == 0) {
        for (int b = threadIdx.x; b < NBIN; b += 256) {
            for (int p = tend[b]; p < tstart[b + 1]; ++p)
                binned[p] = 0xFFFFFFFFu;
        }
    }
    __shared__ int cur[NBIN];
    const int* myb = bbase + (size_t)blockIdx.x * NBIN;
    for (int i = threadIdx.x; i < NBIN; i += 256) cur[i] = myb[i];
    __syncthreads();
    const int base = blockIdx.x * CHUNK2;
    const int4* r4 = reinterpret_cast<const int4*>(row + base);
    const int4* c4 = reinterpret_cast<const int4*>(col + base);
    for (int i = threadIdx.x; i < CHUNK2 / 4; i += 256) {
        int4 r = r4[i], c = c4[i];
        int rr[4] = {r.x, r.y, r.z, r.w};
        int cc[4] = {c.x, c.y, c.z, c.w};
#pragma unroll
        for (int k = 0; k < 4; ++k) {
            int bin = (rr[k] >> RSH) * NCX + (cc[k] >> CSH);
            int pos = atomicAdd(&cur[bin], 1);
            binned[pos] = ((unsigned)rr[k] << 16) | (unsigned)cc[k];
        }
    }
}

// grid (NR, SC), 512 thr: LDS tiles -> per-edge post-leaky scores t (fp16x8),
// stored coalesced at the edge's binned position. NO atomics, NO exp.
__global__ __launch_bounds__(512) void escore_kernel(
    const unsigned* __restrict__ binned, const int* __restrict__ tstart,
    const float* __restrict__ combh, const float* __restrict__ s2h,
    float* __restrict__ sc16)
{
    __shared__ v8h s1t[RNODES];        // 4 KB
    __shared__ v8h s2t[CNODES];        // 32 KB
    const int rx = blockIdx.x;
    const int rbase = rx << RSH;
    const v8h* combv = reinterpret_cast<const v8h*>(combh);
    const v8h* s2v   = reinterpret_cast<const v8h*>(s2h);
    v8h* scv = reinterpret_cast<v8h*>(sc16);

    for (int d = threadIdx.x; d < RNODES; d += 512) {
        int n = rbase + d;
        if (n >= NN) n = NN - 1;
        s1t[d] = combv[(size_t)n * 2];
    }

    const uint4* b4 = reinterpret_cast<const uint4*>(binned);
    for (int cx = blockIdx.y; cx < NCX; cx += SC) {
        __syncthreads();                       // protect s2t from prev readers
        const int cb = cx << CSH;
        for (int j = threadIdx.x; j < CNODES; j += 512) {
            int n = cb + j;
            if (n >= NN) n = NN - 1;
            s2t[j] = s2v[n];
        }
        __syncthreads();
        const int bin = rx * NCX + cx;
        const int p0 = tstart[bin] >> 2, p1 = tstart[bin + 1] >> 2;
        for (int i = p0 + threadIdx.x; i < p1; i += 512) {
            uint4 q = b4[i];
            unsigned pk[4] = {q.x, q.y, q.z, q.w};
            v8h tv[4]; bool ok[4];
#pragma unroll
            for (int k = 0; k < 4; ++k) {
                unsigned d = (pk[k] >> 16) - (unsigned)rbase;
                ok[k] = d < (unsigned)RNODES;            // sentinel pad
                unsigned dcl = ok[k] ? d : 0u;
                unsigned cl  = ok[k] ? ((pk[k] & 0xFFFFu) - (unsigned)cb) : 0u;
                v8h a = s1t[dcl];
                v8h b = s2t[cl];
#pragma unroll
                for (int h = 0; h < H; ++h) {
                    float t = (float)a[h] + (float)b[h];
                    t = fmaxf(t, ALPHA * t);             // leaky here, once
                    tv[k][h] = (_Float16)t;
                }
            }
#pragma unroll
            for (int k = 0; k < 4; ++k)
                if (ok[k]) scv[(size_t)i * 4 + k] = tv[k];  // coalesced 64B/thread
        }
    }
}

// 1 block per range: node-granular counting sort of edge INDICES.
// 2 int LDS atomics per edge; all traffic L2-local (span ~33KB + idx writes).
__global__ __launch_bounds__(512) void node_sort_kernel(
    const unsigned* __restrict__ binned, const int* __restrict__ tstart,
    int* __restrict__ nstart, int* __restrict__ ncnt,
    unsigned* __restrict__ sc2idx)
{
    __shared__ int cnt[RNODES];
    __shared__ int cur[RNODES];
    const int rx = blockIdx.x;
    const int rbase = rx << RSH;
    const int rb = tstart[rx * NCX], re = tstart[(rx + 1) * NCX];
    const int t = threadIdx.x;

    for (int i = t; i < RNODES; i += 512) cnt[i] = 0;
    __syncthreads();
    for (int i = rb + t; i < re; i += 512) {
        unsigned d = (binned[i] >> 16) - (unsigned)rbase;
        if (d < (unsigned)RNODES) atomicAdd(&cnt[d], 1);   // skip sentinels
    }
    __syncthreads();
    if (t == 0) {
        int run = rb;
        for (int d = 0; d < RNODES; ++d) { cur[d] = run; run += cnt[d]; }
    }
    __syncthreads();
    for (int d = t; d < RNODES; d += 512) {
        int n = rbase + d;
        if (n < NN) { nstart[n] = cur[d]; ncnt[n] = cnt[d]; }
    }
    __syncthreads();                     // nstart reads done before cur mutates
    for (int i = rb + t; i < re; i += 512) {
        unsigned d = (binned[i] >> 16) - (unsigned)rbase;
        if (d < (unsigned)RNODES) {
            int pos = atomicAdd(&cur[d], 1);
            sc2idx[pos] = (unsigned)i;   // scattered 4B, within 33KB window (L2)
        }
    }
}

// ATOMIC-FREE accumulation: thread n segment-sums exp(t) over its edges via
// the node-sorted index list (gathers are range-local -> L2-hit, proven-free
// class). Writes lnrec = -log(sum+eps) directly (node_final folded in).
__global__ __launch_bounds__(256) void accum2_kernel(
    const int* __restrict__ nstart, const int* __restrict__ ncnt,
    const unsigned* __restrict__ sc2idx, const float* __restrict__ sc16,
    float* __restrict__ combh)
{
    int n = blockIdx.x * 256 + threadIdx.x;
    if (n >= NN) return;
    const v8h* scv = reinterpret_cast<const v8h*>(sc16);
    const int b = nstart[n], c = ncnt[n];

    float s[H];
#pragma unroll
    for (int h = 0; h < H; ++h) s[h] = 0.f;

    for (int j = 0; j < c; ++j) {
        unsigned idx = sc2idx[b + j];
        v8h t8 = scv[idx];
#pragma unroll
        for (int h = 0; h < H; ++h) s[h] += __expf((float)t8[h]);
    }

    v8h lnh;
#pragma unroll
    for (int h = 0; h < H; ++h) lnh[h] = (_Float16)(-__logf(s[h] + EPS));
    reinterpret_cast<v8h*>(combh)[(size_t)n * 2 + 1] = lnh;
}

// eid-order: 4 edges/thread; 2 miss streams (comb line + s2 line);
// coalesced float4 stores per h-plane.
__global__ __launch_bounds__(256) void edge_out_kernel(
    const int* __restrict__ row, const int* __restrict__ col,
    const float* __restrict__ combh, const float* __restrict__ s2h,
    float* __restrict__ out)
{
    int e0 = (blockIdx.x * 256 + threadIdx.x) * 4;
    if (e0 >= NE) return;
    int4 r4 = *reinterpret_cast<const int4*>(row + e0);
    int4 c4 = *reinterpret_cast<const int4*>(col + e0);
    int rr[4] = {r4.x, r4.y, r4.z, r4.w};
    int cc[4] = {c4.x, c4.y, c4.z, c4.w};
    const v8h* combv = reinterpret_cast<const v8h*>(combh);
    const v8h* s2v   = reinterpret_cast<const v8h*>(s2h);

    float res[4][H];
#pragma unroll
    for (int k = 0; k < 4; ++k) {
        v8h a  = combv[(size_t)rr[k] * 2];
        v8h ln = combv[(size_t)rr[k] * 2 + 1];
        v8h b  = s2v[cc[k]];
#pragma unroll
        for (int h = 0; h < H; ++h) {
            float t = (float)a[h] + (float)b[h];
            t = fmaxf(t, ALPHA * t);
            res[k][h] = __expf(t + (float)ln[h]);   // == exp(leaky(t)) / (sum+eps)
        }
    }
#pragma unroll
    for (int h = 0; h < H; ++h) {
        *reinterpret_cast<float4*>(out + (size_t)h * NE + e0) =
            make_float4(res[0][h], res[1][h], res[2][h], res[3][h]);
    }
}

extern "C" void kernel_launch(void* const* d_in, const int* in_sizes, int n_in,
                              void* d_out, int out_size, void* d_ws, size_t ws_size,
                              hipStream_t stream) {
    const float* x   = (const float*)d_in[0];
    const float* aa  = (const float*)d_in[1];
    const int*   row = (const int*)d_in[2];
    const int*   col = (const int*)d_in[3];
    float* out = (float*)d_out;

    // ws (15.82 MB)
    float* s2h   = (float*)d_ws;                          // NN*4 floats
    float* combh = s2h + (size_t)NN * 4;                  // NN*8 floats
    unsigned* binned = (unsigned*)(combh + (size_t)NN * 8); // ESZ uints
    unsigned* sc2idx = binned + ESZ;                      // ESZ uints
    int* nstart  = (int*)(sc2idx + ESZ);                  // NN
    int* ncnt    = nstart + NN;                           // NN
    int* tstart  = ncnt + NN;                             // NBIN+1
    int* tend    = tstart + NBIN + 1;                     // NBIN
    int* gtot    = tend + NBIN;                           // NBIN

    // out-region scratch (fully consumed before edge_out rewrites out)
    float* sc16 = out;                                    // ESZ*4 floats (25.9M)
    int* counts = (int*)(sc16 + (size_t)ESZ * 4);         // NB2*NBIN (2.5M)
    int* bbase  = counts + (size_t)NB2 * NBIN;            // NB2*NBIN (2.5M)

    node_proj_kernel<<<(NN + 255) / 256, 256, 0, stream>>>(x, aa, combh, s2h);
    bin_count_kernel<<<NB2, 256, 0, stream>>>(row, col, counts);
    scan_a_kernel<<<(NBIN + 255) / 256, 256, 0, stream>>>(counts, gtot);
    scan_b_kernel<<<1, 1024, 0, stream>>>(gtot, tstart, tend);
    scan_c_kernel<<<(NBIN + 255) / 256, 256, 0, stream>>>(counts, tstart, bbase);
    bin_scatter_kernel<<<NB2, 256, 0, stream>>>(row, col, bbase, tstart, tend, binned);
    escore_kernel<<<dim3(NR, SC), 512, 0, stream>>>(binned, tstart, combh, s2h, sc16);
    node_sort_kernel<<<NR, 512, 0, stream>>>(binned, tstart, nstart, ncnt, sc2idx);
    accum2_kernel<<<(NN + 255) / 256, 256, 0, stream>>>(nstart, ncnt, sc2idx, sc16, combh);
    edge_out_kernel<<<(NE / 4 + 255) / 256, 256, 0, stream>>>(row, col, combh, s2h, out);
}